// Round 1
// baseline (1996.151 us; speedup 1.0000x reference)
//
#include <hip/hip_runtime.h>
#include <hip/hip_bf16.h>

// ---------------- constants ----------------
#define N_NODES 50000
#define N_EDGES 600000
#define N_GRAPHS 64

// ---------------- degree / norm ----------------
__global__ __launch_bounds__(256) void deg_count(const int* __restrict__ dst,
                                                 int* __restrict__ degi, int E) {
    int i = blockIdx.x * blockDim.x + threadIdx.x;
    if (i < E) atomicAdd(&degi[dst[i]], 1);
}

__global__ __launch_bounds__(256) void dis_kernel(const int* __restrict__ degi,
                                                  float* __restrict__ dis, int N) {
    int i = blockIdx.x * blockDim.x + threadIdx.x;
    if (i < N) dis[i] = rsqrtf((float)degi[i] + 1.0f);
}

// ---------------- dense matmul: T = act(X) @ W ----------------
// lane = node (64 nodes per wave), wave owns NF consecutive output features.
// F = 4*NF (4 waves per block cover all features). X stride is always 128.
// W addresses are wave-uniform -> scalar loads (broadcast via SGPR).
template <int NF, bool RELU>
__global__ __launch_bounds__(256) void mm_kernel(const float* __restrict__ X,
                                                 const float* __restrict__ W,
                                                 float* __restrict__ T, int N) {
    constexpr int F = NF * 4;
    const int lane = threadIdx.x & 63;
    const int wave = threadIdx.x >> 6;
    const int node = blockIdx.x * 64 + lane;
    const int f0 = __builtin_amdgcn_readfirstlane(wave) * NF;

    const bool valid = node < N;
    const int nclamp = valid ? node : (N - 1);
    const float* xr = X + (size_t)nclamp * 128;

    float acc[NF];
#pragma unroll
    for (int j = 0; j < NF; ++j) acc[j] = 0.0f;

    for (int k0 = 0; k0 < 128; k0 += 4) {
        float4 xv = *reinterpret_cast<const float4*>(xr + k0);
        if (RELU) {
            xv.x = fmaxf(xv.x, 0.0f);
            xv.y = fmaxf(xv.y, 0.0f);
            xv.z = fmaxf(xv.z, 0.0f);
            xv.w = fmaxf(xv.w, 0.0f);
        }
#pragma unroll
        for (int kk = 0; kk < 4; ++kk) {
            const float xs = (kk == 0) ? xv.x : (kk == 1) ? xv.y : (kk == 2) ? xv.z : xv.w;
            const float* wr = W + (size_t)(k0 + kk) * F + f0;
#pragma unroll
            for (int j = 0; j < NF; ++j) acc[j] = fmaf(xs, wr[j], acc[j]);
        }
    }

    if (valid) {
        float* tr = T + (size_t)node * F + f0;
#pragma unroll
        for (int j = 0; j < NF; j += 4) {
            float4 o = {acc[j], acc[j + 1], acc[j + 2], acc[j + 3]};
            *reinterpret_cast<float4*>(tr + j) = o;
        }
    }
}

// ---------------- self-loop + bias init: H = T*dis^2 + b ----------------
template <int FQ>  // FQ = F/4
__global__ __launch_bounds__(256) void init_agg(const float* __restrict__ T,
                                                const float* __restrict__ dis,
                                                const float* __restrict__ b,
                                                float* __restrict__ H, int N) {
    int i = blockIdx.x * blockDim.x + threadIdx.x;
    if (i >= N * FQ) return;
    int node = i / FQ;
    int fq = i - node * FQ;
    float d = dis[node];
    float d2 = d * d;
    float4 t = reinterpret_cast<const float4*>(T)[i];
    float4 bb = reinterpret_cast<const float4*>(b)[fq];
    float4 o = {fmaf(t.x, d2, bb.x), fmaf(t.y, d2, bb.y),
                fmaf(t.z, d2, bb.z), fmaf(t.w, d2, bb.w)};
    reinterpret_cast<float4*>(H)[i] = o;
}

// ---------------- edge scatter: H[dst] += dis[src]*dis[dst] * T[src] ----------------
template <int F>
__global__ __launch_bounds__(256) void edge_kernel(const int* __restrict__ src,
                                                   const int* __restrict__ dst,
                                                   const float* __restrict__ dis,
                                                   const float* __restrict__ T,
                                                   float* __restrict__ AGG, int E) {
    const int lane = threadIdx.x & 63;
    int wid = (blockIdx.x * 256 + threadIdx.x) >> 6;
    const int nw = (gridDim.x * 256) >> 6;
    for (int e = wid; e < E; e += nw) {
        int s = src[e];
        int d = dst[e];
        float nrm = dis[s] * dis[d];
        if (F == 128) {
            float2 v = *reinterpret_cast<const float2*>(T + (size_t)s * 128 + lane * 2);
            float* o = AGG + (size_t)d * 128 + lane * 2;
            atomicAdd(o, nrm * v.x);
            atomicAdd(o + 1, nrm * v.y);
        } else {
            float v = T[(size_t)s * 64 + lane];
            atomicAdd(AGG + (size_t)d * 64 + lane, nrm * v);
        }
    }
}

// ---------------- pooling ----------------
__global__ __launch_bounds__(256) void pool_cnt(const int* __restrict__ batch,
                                                int* __restrict__ cnt, int N) {
    int i = blockIdx.x * blockDim.x + threadIdx.x;
    if (i < N) atomicAdd(&cnt[batch[i]], 1);
}

__global__ __launch_bounds__(256) void pool_sum(const float* __restrict__ H,
                                                const int* __restrict__ batch,
                                                float* __restrict__ sums, int N) {
    const int lane = threadIdx.x & 63;
    int wid = (blockIdx.x * 256 + threadIdx.x) >> 6;
    const int nw = (gridDim.x * 256) >> 6;
    for (int n = wid; n < N; n += nw) {
        int g = batch[n];
        atomicAdd(&sums[g * 64 + lane], H[(size_t)n * 64 + lane]);
    }
}

__global__ __launch_bounds__(256) void pool_fin(const float* __restrict__ sums,
                                                const int* __restrict__ cnt,
                                                float* __restrict__ out) {
    int i = blockIdx.x * blockDim.x + threadIdx.x;
    if (i < N_GRAPHS * 64) {
        int g = i >> 6;
        out[i] = sums[i] / fmaxf((float)cnt[g], 1.0f);
    }
}

// ---------------- launch ----------------
extern "C" void kernel_launch(void* const* d_in, const int* in_sizes, int n_in,
                              void* d_out, int out_size, void* d_ws, size_t ws_size,
                              hipStream_t stream) {
    const float* x = (const float*)d_in[0];
    const int* ei = (const int*)d_in[1];
    const int* batch = (const int*)d_in[2];
    const float* W1 = (const float*)d_in[3];
    const float* b1 = (const float*)d_in[4];
    const float* W2 = (const float*)d_in[5];
    const float* b2 = (const float*)d_in[6];
    const float* W3 = (const float*)d_in[7];
    const float* b3 = (const float*)d_in[8];
    const float* W4 = (const float*)d_in[9];
    const float* b4 = (const float*)d_in[10];

    const int N = N_NODES, E = N_EDGES, G = N_GRAPHS;
    const int* src = ei;
    const int* dst = ei + E;

    // workspace layout
    float* T = (float*)d_ws;                      // N*128 f32
    float* H = T + (size_t)N * 128;               // N*128 f32
    int* degi = (int*)(H + (size_t)N * 128);      // N i32
    float* dis = (float*)(degi + N);              // N f32
    float* sums = dis + N;                        // G*64 f32
    int* cnt = (int*)(sums + G * 64);             // G i32

    hipMemsetAsync(degi, 0, N * sizeof(int), stream);
    hipMemsetAsync(sums, 0, G * 64 * sizeof(float) + G * sizeof(int), stream);

    deg_count<<<(E + 255) / 256, 256, 0, stream>>>(dst, degi, E);
    dis_kernel<<<(N + 255) / 256, 256, 0, stream>>>(degi, dis, N);

    const int MMG = (N + 63) / 64;  // node tiles of 64

    // layer 1: input x (no relu)
    mm_kernel<32, false><<<MMG, 256, 0, stream>>>(x, W1, T, N);
    init_agg<32><<<(N * 32 + 255) / 256, 256, 0, stream>>>(T, dis, b1, H, N);
    edge_kernel<128><<<4096, 256, 0, stream>>>(src, dst, dis, T, H, E);

    // layer 2
    mm_kernel<32, true><<<MMG, 256, 0, stream>>>(H, W2, T, N);
    init_agg<32><<<(N * 32 + 255) / 256, 256, 0, stream>>>(T, dis, b2, H, N);
    edge_kernel<128><<<4096, 256, 0, stream>>>(src, dst, dis, T, H, E);

    // layer 3
    mm_kernel<32, true><<<MMG, 256, 0, stream>>>(H, W3, T, N);
    init_agg<32><<<(N * 32 + 255) / 256, 256, 0, stream>>>(T, dis, b3, H, N);
    edge_kernel<128><<<4096, 256, 0, stream>>>(src, dst, dis, T, H, E);

    // layer 4 (F=64, no relu after)
    mm_kernel<16, true><<<MMG, 256, 0, stream>>>(H, W4, T, N);
    init_agg<16><<<(N * 16 + 255) / 256, 256, 0, stream>>>(T, dis, b4, H, N);
    edge_kernel<64><<<4096, 256, 0, stream>>>(src, dst, dis, T, H, E);

    // global mean pool
    pool_cnt<<<(N + 255) / 256, 256, 0, stream>>>(batch, cnt, N);
    pool_sum<<<2048, 256, 0, stream>>>(H, batch, sums, N);
    pool_fin<<<(G * 64 + 255) / 256, 256, 0, stream>>>(sums, cnt, (float*)d_out);
}

// Round 2
// 720.433 us; speedup vs baseline: 2.7708x; 2.7708x over previous
//
#include <hip/hip_runtime.h>
#include <hip/hip_bf16.h>

// ---------------- constants ----------------
#define N_NODES 50000
#define N_EDGES 600000
#define N_GRAPHS 64

// ---------------- degree / norm ----------------
__global__ __launch_bounds__(256) void deg_count(const int* __restrict__ dst,
                                                 int* __restrict__ degi, int E) {
    int i = blockIdx.x * blockDim.x + threadIdx.x;
    if (i < E) atomicAdd(&degi[dst[i]], 1);
}

__global__ __launch_bounds__(256) void dis_kernel(const int* __restrict__ degi,
                                                  float* __restrict__ dis, int N) {
    int i = blockIdx.x * blockDim.x + threadIdx.x;
    if (i < N) dis[i] = rsqrtf((float)degi[i] + 1.0f);
}

// ---------------- prefix scan (3-kernel hierarchical) ----------------
__global__ __launch_bounds__(256) void scan_block(const int* __restrict__ in,
                                                  int* __restrict__ excl,
                                                  int* __restrict__ bsum, int N) {
    __shared__ int s[256];
    int i = blockIdx.x * 256 + threadIdx.x;
    int v = (i < N) ? in[i] : 0;
    s[threadIdx.x] = v;
    __syncthreads();
#pragma unroll
    for (int off = 1; off < 256; off <<= 1) {
        int t = (threadIdx.x >= off) ? s[threadIdx.x - off] : 0;
        __syncthreads();
        s[threadIdx.x] += t;
        __syncthreads();
    }
    if (i < N) excl[i] = s[threadIdx.x] - v;
    if (threadIdx.x == 255) bsum[blockIdx.x] = s[255];
}

__global__ __launch_bounds__(256) void scan_top(const int* __restrict__ bsum,
                                                int* __restrict__ boff, int NB) {
    __shared__ int s[256];
    int v = (threadIdx.x < NB) ? bsum[threadIdx.x] : 0;
    s[threadIdx.x] = v;
    __syncthreads();
#pragma unroll
    for (int off = 1; off < 256; off <<= 1) {
        int t = (threadIdx.x >= off) ? s[threadIdx.x - off] : 0;
        __syncthreads();
        s[threadIdx.x] += t;
        __syncthreads();
    }
    if (threadIdx.x < NB) boff[threadIdx.x] = s[threadIdx.x] - v;
}

__global__ __launch_bounds__(256) void scan_fix(const int* __restrict__ excl,
                                                const int* __restrict__ boff,
                                                int* __restrict__ rowptr,
                                                int* __restrict__ cursor, int N, int E) {
    int i = blockIdx.x * 256 + threadIdx.x;
    if (i < N) {
        int r = excl[i] + boff[blockIdx.x];
        rowptr[i] = r;
        cursor[i] = r;
    }
    if (i == 0) rowptr[N] = E;
}

// ---------------- CSR fill: pack {src, norm} per edge ----------------
__global__ __launch_bounds__(256) void csr_fill(const int* __restrict__ src,
                                                const int* __restrict__ dst,
                                                const float* __restrict__ dis,
                                                int* __restrict__ cursor,
                                                int2* __restrict__ csr, int E) {
    int e = blockIdx.x * blockDim.x + threadIdx.x;
    if (e >= E) return;
    int s = src[e];
    int d = dst[e];
    float nrm = dis[s] * dis[d];
    int pos = atomicAdd(&cursor[d], 1);
    csr[pos] = make_int2(s, __float_as_int(nrm));
}

// ---------------- dense matmul: T = act(X) @ W ----------------
template <int NF, bool RELU>
__global__ __launch_bounds__(256) void mm_kernel(const float* __restrict__ X,
                                                 const float* __restrict__ W,
                                                 float* __restrict__ T, int N) {
    constexpr int F = NF * 4;
    const int lane = threadIdx.x & 63;
    const int wave = threadIdx.x >> 6;
    const int node = blockIdx.x * 64 + lane;
    const int f0 = __builtin_amdgcn_readfirstlane(wave) * NF;

    const bool valid = node < N;
    const int nclamp = valid ? node : (N - 1);
    const float* xr = X + (size_t)nclamp * 128;

    float acc[NF];
#pragma unroll
    for (int j = 0; j < NF; ++j) acc[j] = 0.0f;

    for (int k0 = 0; k0 < 128; k0 += 4) {
        float4 xv = *reinterpret_cast<const float4*>(xr + k0);
        if (RELU) {
            xv.x = fmaxf(xv.x, 0.0f);
            xv.y = fmaxf(xv.y, 0.0f);
            xv.z = fmaxf(xv.z, 0.0f);
            xv.w = fmaxf(xv.w, 0.0f);
        }
#pragma unroll
        for (int kk = 0; kk < 4; ++kk) {
            const float xs = (kk == 0) ? xv.x : (kk == 1) ? xv.y : (kk == 2) ? xv.z : xv.w;
            const float* wr = W + (size_t)(k0 + kk) * F + f0;
#pragma unroll
            for (int j = 0; j < NF; ++j) acc[j] = fmaf(xs, wr[j], acc[j]);
        }
    }

    if (valid) {
        float* tr = T + (size_t)node * F + f0;
#pragma unroll
        for (int j = 0; j < NF; j += 4) {
            float4 o = {acc[j], acc[j + 1], acc[j + 2], acc[j + 3]};
            *reinterpret_cast<float4*>(tr + j) = o;
        }
    }
}

// ---------------- gather aggregation ----------------
// one wave per node; lanes cover features. acc init = self-loop + bias.
// H[n] = T[n]*dis[n]^2 + b + sum_{e: dst=n} norm_e * T[src_e]
template <int F>
__global__ __launch_bounds__(256) void agg_kernel(const int* __restrict__ rowptr,
                                                  const int2* __restrict__ csr,
                                                  const float* __restrict__ dis,
                                                  const float* __restrict__ b,
                                                  const float* __restrict__ T,
                                                  float* __restrict__ H, int N) {
    const int lane = threadIdx.x & 63;
    const int node = (blockIdx.x * 256 + threadIdx.x) >> 6;
    if (node >= N) return;

    const int beg = rowptr[node];
    const int end = rowptr[node + 1];
    const float d = dis[node];
    const float d2 = d * d;

    if (F == 128) {
        float2 t = *reinterpret_cast<const float2*>(T + (size_t)node * 128 + lane * 2);
        float2 bb = *reinterpret_cast<const float2*>(b + lane * 2);
        float ax = fmaf(t.x, d2, bb.x);
        float ay = fmaf(t.y, d2, bb.y);
        for (int p = beg; p < end; ++p) {
            int2 ed = csr[p];
            float nrm = __int_as_float(ed.y);
            float2 v = *reinterpret_cast<const float2*>(T + (size_t)ed.x * 128 + lane * 2);
            ax = fmaf(nrm, v.x, ax);
            ay = fmaf(nrm, v.y, ay);
        }
        *reinterpret_cast<float2*>(H + (size_t)node * 128 + lane * 2) = make_float2(ax, ay);
    } else {  // F == 64
        float t = T[(size_t)node * 64 + lane];
        float a = fmaf(t, d2, b[lane]);
        for (int p = beg; p < end; ++p) {
            int2 ed = csr[p];
            float nrm = __int_as_float(ed.y);
            a = fmaf(nrm, T[(size_t)ed.x * 64 + lane], a);
        }
        H[(size_t)node * 64 + lane] = a;
    }
}

// ---------------- pooling ----------------
__global__ __launch_bounds__(256) void pool_cnt(const int* __restrict__ batch,
                                                int* __restrict__ cnt, int N) {
    int i = blockIdx.x * blockDim.x + threadIdx.x;
    if (i < N) atomicAdd(&cnt[batch[i]], 1);
}

__global__ __launch_bounds__(256) void pool_sum(const float* __restrict__ H,
                                                const int* __restrict__ batch,
                                                float* __restrict__ sums, int N) {
    const int lane = threadIdx.x & 63;
    int wid = (blockIdx.x * 256 + threadIdx.x) >> 6;
    const int nw = (gridDim.x * 256) >> 6;
    for (int n = wid; n < N; n += nw) {
        int g = batch[n];
        atomicAdd(&sums[g * 64 + lane], H[(size_t)n * 64 + lane]);
    }
}

__global__ __launch_bounds__(256) void pool_fin(const float* __restrict__ sums,
                                                const int* __restrict__ cnt,
                                                float* __restrict__ out) {
    int i = blockIdx.x * blockDim.x + threadIdx.x;
    if (i < N_GRAPHS * 64) {
        int g = i >> 6;
        out[i] = sums[i] / fmaxf((float)cnt[g], 1.0f);
    }
}

// ---------------- launch ----------------
extern "C" void kernel_launch(void* const* d_in, const int* in_sizes, int n_in,
                              void* d_out, int out_size, void* d_ws, size_t ws_size,
                              hipStream_t stream) {
    const float* x = (const float*)d_in[0];
    const int* ei = (const int*)d_in[1];
    const int* batch = (const int*)d_in[2];
    const float* W1 = (const float*)d_in[3];
    const float* b1 = (const float*)d_in[4];
    const float* W2 = (const float*)d_in[5];
    const float* b2 = (const float*)d_in[6];
    const float* W3 = (const float*)d_in[7];
    const float* b3 = (const float*)d_in[8];
    const float* W4 = (const float*)d_in[9];
    const float* b4 = (const float*)d_in[10];

    const int N = N_NODES, E = N_EDGES, G = N_GRAPHS;
    const int* src = ei;
    const int* dst = ei + E;

    // workspace layout
    float* T = (float*)d_ws;                      // N*128 f32
    float* H = T + (size_t)N * 128;               // N*128 f32
    int* degi = (int*)(H + (size_t)N * 128);      // N i32
    float* dis = (float*)(degi + N);              // N f32
    int* rowptr = (int*)(dis + N);                // N+1 i32
    int* cursor = rowptr + (N + 1);               // N i32
    int* excl = cursor + N;                       // N i32
    int* bsum = excl + N;                         // 256 i32
    int* boff = bsum + 256;                       // 256 i32
    int2* csr = (int2*)(boff + 256);              // E int2
    float* sums = (float*)(csr + E);              // G*64 f32
    int* cnt = (int*)(sums + G * 64);             // G i32

    hipMemsetAsync(degi, 0, N * sizeof(int), stream);
    hipMemsetAsync(sums, 0, G * 64 * sizeof(float) + G * sizeof(int), stream);

    // ---- CSR build (once, reused by all 4 layers) ----
    const int NB = (N + 255) / 256;  // 196
    deg_count<<<(E + 255) / 256, 256, 0, stream>>>(dst, degi, E);
    dis_kernel<<<NB, 256, 0, stream>>>(degi, dis, N);
    scan_block<<<NB, 256, 0, stream>>>(degi, excl, bsum, N);
    scan_top<<<1, 256, 0, stream>>>(bsum, boff, NB);
    scan_fix<<<NB, 256, 0, stream>>>(excl, boff, rowptr, cursor, N, E);
    csr_fill<<<(E + 255) / 256, 256, 0, stream>>>(src, dst, dis, cursor, csr, E);

    const int MMG = (N + 63) / 64;       // mm: 64 nodes per block
    const int AGG = (N * 64 + 255) / 256;  // agg: 4 nodes per block

    // layer 1: input x (no relu)
    mm_kernel<32, false><<<MMG, 256, 0, stream>>>(x, W1, T, N);
    agg_kernel<128><<<AGG, 256, 0, stream>>>(rowptr, csr, dis, b1, T, H, N);

    // layer 2
    mm_kernel<32, true><<<MMG, 256, 0, stream>>>(H, W2, T, N);
    agg_kernel<128><<<AGG, 256, 0, stream>>>(rowptr, csr, dis, b2, T, H, N);

    // layer 3
    mm_kernel<32, true><<<MMG, 256, 0, stream>>>(H, W3, T, N);
    agg_kernel<128><<<AGG, 256, 0, stream>>>(rowptr, csr, dis, b3, T, H, N);

    // layer 4 (F=64, no relu after)
    mm_kernel<16, true><<<MMG, 256, 0, stream>>>(H, W4, T, N);
    agg_kernel<64><<<AGG, 256, 0, stream>>>(rowptr, csr, dis, b4, T, H, N);

    // global mean pool
    pool_cnt<<<NB, 256, 0, stream>>>(batch, cnt, N);
    pool_sum<<<2048, 256, 0, stream>>>(H, batch, sums, N);
    pool_fin<<<(G * 64 + 255) / 256, 256, 0, stream>>>(sums, cnt, (float*)d_out);
}

// Round 3
// 528.044 us; speedup vs baseline: 3.7803x; 1.3643x over previous
//
#include <hip/hip_runtime.h>
#include <hip/hip_bf16.h>

// ---------------- constants ----------------
#define N_NODES 50000
#define N_EDGES 600000
#define N_GRAPHS 64

// ---------------- degree / norm ----------------
__global__ __launch_bounds__(256) void deg_count(const int* __restrict__ dst,
                                                 int* __restrict__ degi, int E) {
    int i = blockIdx.x * blockDim.x + threadIdx.x;
    if (i < E) atomicAdd(&degi[dst[i]], 1);
}

__global__ __launch_bounds__(256) void dis_kernel(const int* __restrict__ degi,
                                                  float* __restrict__ dis, int N) {
    int i = blockIdx.x * blockDim.x + threadIdx.x;
    if (i < N) dis[i] = rsqrtf((float)degi[i] + 1.0f);
}

// ---------------- prefix scan (3-kernel hierarchical) ----------------
__global__ __launch_bounds__(256) void scan_block(const int* __restrict__ in,
                                                  int* __restrict__ excl,
                                                  int* __restrict__ bsum, int N) {
    __shared__ int s[256];
    int i = blockIdx.x * 256 + threadIdx.x;
    int v = (i < N) ? in[i] : 0;
    s[threadIdx.x] = v;
    __syncthreads();
#pragma unroll
    for (int off = 1; off < 256; off <<= 1) {
        int t = (threadIdx.x >= off) ? s[threadIdx.x - off] : 0;
        __syncthreads();
        s[threadIdx.x] += t;
        __syncthreads();
    }
    if (i < N) excl[i] = s[threadIdx.x] - v;
    if (threadIdx.x == 255) bsum[blockIdx.x] = s[255];
}

__global__ __launch_bounds__(256) void scan_top(const int* __restrict__ bsum,
                                                int* __restrict__ boff, int NB) {
    __shared__ int s[256];
    int v = (threadIdx.x < NB) ? bsum[threadIdx.x] : 0;
    s[threadIdx.x] = v;
    __syncthreads();
#pragma unroll
    for (int off = 1; off < 256; off <<= 1) {
        int t = (threadIdx.x >= off) ? s[threadIdx.x - off] : 0;
        __syncthreads();
        s[threadIdx.x] += t;
        __syncthreads();
    }
    if (threadIdx.x < NB) boff[threadIdx.x] = s[threadIdx.x] - v;
}

__global__ __launch_bounds__(256) void scan_fix(const int* __restrict__ excl,
                                                const int* __restrict__ boff,
                                                int* __restrict__ rowptr,
                                                int* __restrict__ cursor, int N, int E) {
    int i = blockIdx.x * 256 + threadIdx.x;
    if (i < N) {
        int r = excl[i] + boff[blockIdx.x];
        rowptr[i] = r;
        cursor[i] = r;
    }
    if (i == 0) rowptr[N] = E;
}

// ---------------- CSR fill: pack {src, norm} per edge ----------------
__global__ __launch_bounds__(256) void csr_fill(const int* __restrict__ src,
                                                const int* __restrict__ dst,
                                                const float* __restrict__ dis,
                                                int* __restrict__ cursor,
                                                int2* __restrict__ csr, int E) {
    int e = blockIdx.x * blockDim.x + threadIdx.x;
    if (e >= E) return;
    int s = src[e];
    int d = dst[e];
    float nrm = dis[s] * dis[d];
    int pos = atomicAdd(&cursor[d], 1);
    csr[pos] = make_int2(s, __float_as_int(nrm));
}

// ---------------- dense matmul: T = act(X) @ W ----------------
template <int NF, bool RELU>
__global__ __launch_bounds__(256) void mm_kernel(const float* __restrict__ X,
                                                 const float* __restrict__ W,
                                                 float* __restrict__ T, int N) {
    constexpr int F = NF * 4;
    const int lane = threadIdx.x & 63;
    const int wave = threadIdx.x >> 6;
    const int node = blockIdx.x * 64 + lane;
    const int f0 = __builtin_amdgcn_readfirstlane(wave) * NF;

    const bool valid = node < N;
    const int nclamp = valid ? node : (N - 1);
    const float* xr = X + (size_t)nclamp * 128;

    float acc[NF];
#pragma unroll
    for (int j = 0; j < NF; ++j) acc[j] = 0.0f;

    for (int k0 = 0; k0 < 128; k0 += 4) {
        float4 xv = *reinterpret_cast<const float4*>(xr + k0);
        if (RELU) {
            xv.x = fmaxf(xv.x, 0.0f);
            xv.y = fmaxf(xv.y, 0.0f);
            xv.z = fmaxf(xv.z, 0.0f);
            xv.w = fmaxf(xv.w, 0.0f);
        }
#pragma unroll
        for (int kk = 0; kk < 4; ++kk) {
            const float xs = (kk == 0) ? xv.x : (kk == 1) ? xv.y : (kk == 2) ? xv.z : xv.w;
            const float* wr = W + (size_t)(k0 + kk) * F + f0;
#pragma unroll
            for (int j = 0; j < NF; ++j) acc[j] = fmaf(xs, wr[j], acc[j]);
        }
    }

    if (valid) {
        float* tr = T + (size_t)node * F + f0;
#pragma unroll
        for (int j = 0; j < NF; j += 4) {
            float4 o = {acc[j], acc[j + 1], acc[j + 2], acc[j + 3]};
            *reinterpret_cast<float4*>(tr + j) = o;
        }
    }
}

// ---------------- gather aggregation ----------------
// one wave per node; lanes cover features. acc init = self-loop + bias.
// H[n] = T[n]*dis[n]^2 + b + sum_{e: dst=n} norm_e * T[src_e]
template <int F>
__global__ __launch_bounds__(256) void agg_kernel(const int* __restrict__ rowptr,
                                                  const int2* __restrict__ csr,
                                                  const float* __restrict__ dis,
                                                  const float* __restrict__ b,
                                                  const float* __restrict__ T,
                                                  float* __restrict__ H, int N) {
    const int lane = threadIdx.x & 63;
    const int node = (blockIdx.x * 256 + threadIdx.x) >> 6;
    if (node >= N) return;

    const int beg = rowptr[node];
    const int end = rowptr[node + 1];
    const float d = dis[node];
    const float d2 = d * d;

    if (F == 128) {
        float2 t = *reinterpret_cast<const float2*>(T + (size_t)node * 128 + lane * 2);
        float2 bb = *reinterpret_cast<const float2*>(b + lane * 2);
        float ax = fmaf(t.x, d2, bb.x);
        float ay = fmaf(t.y, d2, bb.y);
        for (int p = beg; p < end; ++p) {
            int2 ed = csr[p];
            float nrm = __int_as_float(ed.y);
            float2 v = *reinterpret_cast<const float2*>(T + (size_t)ed.x * 128 + lane * 2);
            ax = fmaf(nrm, v.x, ax);
            ay = fmaf(nrm, v.y, ay);
        }
        *reinterpret_cast<float2*>(H + (size_t)node * 128 + lane * 2) = make_float2(ax, ay);
    } else {  // F == 64
        float t = T[(size_t)node * 64 + lane];
        float a = fmaf(t, d2, b[lane]);
        for (int p = beg; p < end; ++p) {
            int2 ed = csr[p];
            float nrm = __int_as_float(ed.y);
            a = fmaf(nrm, T[(size_t)ed.x * 64 + lane], a);
        }
        H[(size_t)node * 64 + lane] = a;
    }
}

// ---------------- pooling (batch is SORTED -> contiguous graph segments) ----------------
// gstart[g] = first node index with batch[node] >= g, for g in [0, 64]
__global__ __launch_bounds__(128) void graph_bounds(const int* __restrict__ batch,
                                                    int* __restrict__ gstart, int N) {
    int g = threadIdx.x;
    if (g > N_GRAPHS) return;
    int lo = 0, hi = N;
    while (lo < hi) {
        int mid = (lo + hi) >> 1;
        if (batch[mid] < g) lo = mid + 1; else hi = mid;
    }
    gstart[g] = lo;
}

// one block (4 waves) per graph; lane = feature; wave-strided over node segment
__global__ __launch_bounds__(256) void pool_graph(const float* __restrict__ H,
                                                  const int* __restrict__ gstart,
                                                  float* __restrict__ out) {
    const int g = blockIdx.x;
    const int beg = gstart[g];
    const int end = gstart[g + 1];
    const int lane = threadIdx.x & 63;
    const int wave = threadIdx.x >> 6;

    float acc = 0.0f;
    for (int n = beg + wave; n < end; n += 4)
        acc += H[(size_t)n * 64 + lane];

    __shared__ float s[4][64];
    s[wave][lane] = acc;
    __syncthreads();
    if (wave == 0) {
        float v = s[0][lane] + s[1][lane] + s[2][lane] + s[3][lane];
        float c = (float)(end - beg);
        out[g * 64 + lane] = v / fmaxf(c, 1.0f);
    }
}

// ---------------- launch ----------------
extern "C" void kernel_launch(void* const* d_in, const int* in_sizes, int n_in,
                              void* d_out, int out_size, void* d_ws, size_t ws_size,
                              hipStream_t stream) {
    const float* x = (const float*)d_in[0];
    const int* ei = (const int*)d_in[1];
    const int* batch = (const int*)d_in[2];
    const float* W1 = (const float*)d_in[3];
    const float* b1 = (const float*)d_in[4];
    const float* W2 = (const float*)d_in[5];
    const float* b2 = (const float*)d_in[6];
    const float* W3 = (const float*)d_in[7];
    const float* b3 = (const float*)d_in[8];
    const float* W4 = (const float*)d_in[9];
    const float* b4 = (const float*)d_in[10];

    const int N = N_NODES, E = N_EDGES;
    const int* src = ei;
    const int* dst = ei + E;

    // workspace layout
    float* T = (float*)d_ws;                      // N*128 f32
    float* H = T + (size_t)N * 128;               // N*128 f32
    int* degi = (int*)(H + (size_t)N * 128);      // N i32
    float* dis = (float*)(degi + N);              // N f32
    int* rowptr = (int*)(dis + N);                // N+1 i32
    int* cursor = rowptr + (N + 1);               // N i32
    int* excl = cursor + N;                       // N i32
    int* bsum = excl + N;                         // 256 i32
    int* boff = bsum + 256;                       // 256 i32
    int2* csr = (int2*)(boff + 256);              // E int2
    int* gstart = (int*)(csr + E);                // 65 i32

    hipMemsetAsync(degi, 0, N * sizeof(int), stream);

    // ---- CSR build (once, reused by all 4 layers) ----
    const int NB = (N + 255) / 256;  // 196
    deg_count<<<(E + 255) / 256, 256, 0, stream>>>(dst, degi, E);
    dis_kernel<<<NB, 256, 0, stream>>>(degi, dis, N);
    scan_block<<<NB, 256, 0, stream>>>(degi, excl, bsum, N);
    scan_top<<<1, 256, 0, stream>>>(bsum, boff, NB);
    scan_fix<<<NB, 256, 0, stream>>>(excl, boff, rowptr, cursor, N, E);
    csr_fill<<<(E + 255) / 256, 256, 0, stream>>>(src, dst, dis, cursor, csr, E);
    graph_bounds<<<1, 128, 0, stream>>>(batch, gstart, N);

    const int MMG = (N + 63) / 64;         // mm: 64 nodes per block
    const int AGG = (N * 64 + 255) / 256;  // agg: 4 nodes per block

    // layer 1: input x (no relu)
    mm_kernel<32, false><<<MMG, 256, 0, stream>>>(x, W1, T, N);
    agg_kernel<128><<<AGG, 256, 0, stream>>>(rowptr, csr, dis, b1, T, H, N);

    // layer 2
    mm_kernel<32, true><<<MMG, 256, 0, stream>>>(H, W2, T, N);
    agg_kernel<128><<<AGG, 256, 0, stream>>>(rowptr, csr, dis, b2, T, H, N);

    // layer 3
    mm_kernel<32, true><<<MMG, 256, 0, stream>>>(H, W3, T, N);
    agg_kernel<128><<<AGG, 256, 0, stream>>>(rowptr, csr, dis, b3, T, H, N);

    // layer 4 (F=64, no relu after)
    mm_kernel<16, true><<<MMG, 256, 0, stream>>>(H, W4, T, N);
    agg_kernel<64><<<AGG, 256, 0, stream>>>(rowptr, csr, dis, b4, T, H, N);

    // global mean pool (no atomics; batch sorted)
    pool_graph<<<N_GRAPHS, 256, 0, stream>>>(H, gstart, (float*)d_out);
}

// Round 4
// 369.488 us; speedup vs baseline: 5.4025x; 1.4291x over previous
//
#include <hip/hip_runtime.h>
#include <hip/hip_bf16.h>

// ---------------- constants ----------------
#define N_NODES 50000
#define N_EDGES 600000
#define N_GRAPHS 64

// ---------------- bf16 helpers (round-to-nearest-even) ----------------
__device__ __forceinline__ unsigned short f2bf(float f) {
    unsigned int u = __float_as_uint(f);
    unsigned int r = u + 0x7fffu + ((u >> 16) & 1u);
    return (unsigned short)(r >> 16);
}
__device__ __forceinline__ float bf_lo(unsigned int u) {  // low ushort -> f32
    return __uint_as_float(u << 16);
}
__device__ __forceinline__ float bf_hi(unsigned int u) {  // high ushort -> f32
    return __uint_as_float(u & 0xffff0000u);
}
__device__ __forceinline__ float bf1(unsigned short s) {
    return __uint_as_float((unsigned int)s << 16);
}

// ---------------- degree / norm ----------------
__global__ __launch_bounds__(256) void deg_count(const int* __restrict__ dst,
                                                 int* __restrict__ degi, int E) {
    int i = blockIdx.x * blockDim.x + threadIdx.x;
    if (i < E) atomicAdd(&degi[dst[i]], 1);
}

__global__ __launch_bounds__(256) void dis_kernel(const int* __restrict__ degi,
                                                  float* __restrict__ dis, int N) {
    int i = blockIdx.x * blockDim.x + threadIdx.x;
    if (i < N) dis[i] = rsqrtf((float)degi[i] + 1.0f);
}

// ---------------- prefix scan (3-kernel hierarchical) ----------------
__global__ __launch_bounds__(256) void scan_block(const int* __restrict__ in,
                                                  int* __restrict__ excl,
                                                  int* __restrict__ bsum, int N) {
    __shared__ int s[256];
    int i = blockIdx.x * 256 + threadIdx.x;
    int v = (i < N) ? in[i] : 0;
    s[threadIdx.x] = v;
    __syncthreads();
#pragma unroll
    for (int off = 1; off < 256; off <<= 1) {
        int t = (threadIdx.x >= off) ? s[threadIdx.x - off] : 0;
        __syncthreads();
        s[threadIdx.x] += t;
        __syncthreads();
    }
    if (i < N) excl[i] = s[threadIdx.x] - v;
    if (threadIdx.x == 255) bsum[blockIdx.x] = s[255];
}

__global__ __launch_bounds__(256) void scan_top(const int* __restrict__ bsum,
                                                int* __restrict__ boff, int NB) {
    __shared__ int s[256];
    int v = (threadIdx.x < NB) ? bsum[threadIdx.x] : 0;
    s[threadIdx.x] = v;
    __syncthreads();
#pragma unroll
    for (int off = 1; off < 256; off <<= 1) {
        int t = (threadIdx.x >= off) ? s[threadIdx.x - off] : 0;
        __syncthreads();
        s[threadIdx.x] += t;
        __syncthreads();
    }
    if (threadIdx.x < NB) boff[threadIdx.x] = s[threadIdx.x] - v;
}

__global__ __launch_bounds__(256) void scan_fix(const int* __restrict__ excl,
                                                const int* __restrict__ boff,
                                                int* __restrict__ rowptr,
                                                int* __restrict__ cursor, int N, int E) {
    int i = blockIdx.x * 256 + threadIdx.x;
    if (i < N) {
        int r = excl[i] + boff[blockIdx.x];
        rowptr[i] = r;
        cursor[i] = r;
    }
    if (i == 0) rowptr[N] = E;
}

// ---------------- CSR fill: pack {src, norm} per edge ----------------
__global__ __launch_bounds__(256) void csr_fill(const int* __restrict__ src,
                                                const int* __restrict__ dst,
                                                const float* __restrict__ dis,
                                                int* __restrict__ cursor,
                                                int2* __restrict__ csr, int E) {
    int e = blockIdx.x * blockDim.x + threadIdx.x;
    if (e >= E) return;
    int s = src[e];
    int d = dst[e];
    float nrm = dis[s] * dis[d];
    int pos = atomicAdd(&cursor[d], 1);
    csr[pos] = make_int2(s, __float_as_int(nrm));
}

// ---------------- dense matmul: T = act(X) @ W  (T stored as bf16) ----------------
template <int NF, bool RELU>
__global__ __launch_bounds__(256) void mm_kernel(const float* __restrict__ X,
                                                 const float* __restrict__ W,
                                                 unsigned short* __restrict__ T, int N) {
    constexpr int F = NF * 4;
    const int lane = threadIdx.x & 63;
    const int wave = threadIdx.x >> 6;
    const int node = blockIdx.x * 64 + lane;
    const int f0 = __builtin_amdgcn_readfirstlane(wave) * NF;

    const bool valid = node < N;
    const int nclamp = valid ? node : (N - 1);
    const float* xr = X + (size_t)nclamp * 128;

    float acc[NF];
#pragma unroll
    for (int j = 0; j < NF; ++j) acc[j] = 0.0f;

    for (int k0 = 0; k0 < 128; k0 += 4) {
        float4 xv = *reinterpret_cast<const float4*>(xr + k0);
        if (RELU) {
            xv.x = fmaxf(xv.x, 0.0f);
            xv.y = fmaxf(xv.y, 0.0f);
            xv.z = fmaxf(xv.z, 0.0f);
            xv.w = fmaxf(xv.w, 0.0f);
        }
#pragma unroll
        for (int kk = 0; kk < 4; ++kk) {
            const float xs = (kk == 0) ? xv.x : (kk == 1) ? xv.y : (kk == 2) ? xv.z : xv.w;
            const float* wr = W + (size_t)(k0 + kk) * F + f0;
#pragma unroll
            for (int j = 0; j < NF; ++j) acc[j] = fmaf(xs, wr[j], acc[j]);
        }
    }

    if (valid) {
        unsigned short* tr = T + (size_t)node * F + f0;
#pragma unroll
        for (int j = 0; j < NF; j += 4) {
            ushort4 o = {f2bf(acc[j]), f2bf(acc[j + 1]), f2bf(acc[j + 2]), f2bf(acc[j + 3])};
            *reinterpret_cast<ushort4*>(tr + j) = o;
        }
    }
}

// ---------------- gather aggregation (bf16 rows, f32 accumulate) ----------------
// one wave per node; lanes cover features. acc init = self-loop + bias.
// H[n] = T[n]*dis[n]^2 + b + sum_{e: dst=n} norm_e * T[src_e]
template <int F>
__global__ __launch_bounds__(256) void agg_kernel(const int* __restrict__ rowptr,
                                                  const int2* __restrict__ csr,
                                                  const float* __restrict__ dis,
                                                  const float* __restrict__ b,
                                                  const unsigned short* __restrict__ T,
                                                  float* __restrict__ H, int N) {
    const int lane = threadIdx.x & 63;
    const int node = (blockIdx.x * 256 + threadIdx.x) >> 6;
    if (node >= N) return;

    const int beg = rowptr[node];
    const int end = rowptr[node + 1];
    const float d = dis[node];
    const float d2 = d * d;

    if (F == 128) {
        unsigned int selfv =
            *reinterpret_cast<const unsigned int*>(T + (size_t)node * 128 + lane * 2);
        float2 bb = *reinterpret_cast<const float2*>(b + lane * 2);
        float ax = fmaf(bf_lo(selfv), d2, bb.x);
        float ay = fmaf(bf_hi(selfv), d2, bb.y);

        int p = beg;
        for (; p + 4 <= end; p += 4) {
            int2 e0 = csr[p], e1 = csr[p + 1], e2 = csr[p + 2], e3 = csr[p + 3];
            unsigned int r0 =
                *reinterpret_cast<const unsigned int*>(T + (size_t)e0.x * 128 + lane * 2);
            unsigned int r1 =
                *reinterpret_cast<const unsigned int*>(T + (size_t)e1.x * 128 + lane * 2);
            unsigned int r2 =
                *reinterpret_cast<const unsigned int*>(T + (size_t)e2.x * 128 + lane * 2);
            unsigned int r3 =
                *reinterpret_cast<const unsigned int*>(T + (size_t)e3.x * 128 + lane * 2);
            float n0 = __int_as_float(e0.y), n1 = __int_as_float(e1.y);
            float n2 = __int_as_float(e2.y), n3 = __int_as_float(e3.y);
            ax = fmaf(n0, bf_lo(r0), ax); ay = fmaf(n0, bf_hi(r0), ay);
            ax = fmaf(n1, bf_lo(r1), ax); ay = fmaf(n1, bf_hi(r1), ay);
            ax = fmaf(n2, bf_lo(r2), ax); ay = fmaf(n2, bf_hi(r2), ay);
            ax = fmaf(n3, bf_lo(r3), ax); ay = fmaf(n3, bf_hi(r3), ay);
        }
        for (; p < end; ++p) {
            int2 ed = csr[p];
            float nrm = __int_as_float(ed.y);
            unsigned int r =
                *reinterpret_cast<const unsigned int*>(T + (size_t)ed.x * 128 + lane * 2);
            ax = fmaf(nrm, bf_lo(r), ax);
            ay = fmaf(nrm, bf_hi(r), ay);
        }
        *reinterpret_cast<float2*>(H + (size_t)node * 128 + lane * 2) = make_float2(ax, ay);
    } else {  // F == 64
        float a = fmaf(bf1(T[(size_t)node * 64 + lane]), d2, b[lane]);

        int p = beg;
        for (; p + 4 <= end; p += 4) {
            int2 e0 = csr[p], e1 = csr[p + 1], e2 = csr[p + 2], e3 = csr[p + 3];
            unsigned short v0 = T[(size_t)e0.x * 64 + lane];
            unsigned short v1 = T[(size_t)e1.x * 64 + lane];
            unsigned short v2 = T[(size_t)e2.x * 64 + lane];
            unsigned short v3 = T[(size_t)e3.x * 64 + lane];
            a = fmaf(__int_as_float(e0.y), bf1(v0), a);
            a = fmaf(__int_as_float(e1.y), bf1(v1), a);
            a = fmaf(__int_as_float(e2.y), bf1(v2), a);
            a = fmaf(__int_as_float(e3.y), bf1(v3), a);
        }
        for (; p < end; ++p) {
            int2 ed = csr[p];
            a = fmaf(__int_as_float(ed.y), bf1(T[(size_t)ed.x * 64 + lane]), a);
        }
        H[(size_t)node * 64 + lane] = a;
    }
}

// ---------------- pooling (batch is SORTED -> contiguous graph segments) ----------------
__global__ __launch_bounds__(128) void graph_bounds(const int* __restrict__ batch,
                                                    int* __restrict__ gstart, int N) {
    int g = threadIdx.x;
    if (g > N_GRAPHS) return;
    int lo = 0, hi = N;
    while (lo < hi) {
        int mid = (lo + hi) >> 1;
        if (batch[mid] < g) lo = mid + 1; else hi = mid;
    }
    gstart[g] = lo;
}

__global__ __launch_bounds__(256) void pool_graph(const float* __restrict__ H,
                                                  const int* __restrict__ gstart,
                                                  float* __restrict__ out) {
    const int g = blockIdx.x;
    const int beg = gstart[g];
    const int end = gstart[g + 1];
    const int lane = threadIdx.x & 63;
    const int wave = threadIdx.x >> 6;

    float acc = 0.0f;
    for (int n = beg + wave; n < end; n += 4)
        acc += H[(size_t)n * 64 + lane];

    __shared__ float s[4][64];
    s[wave][lane] = acc;
    __syncthreads();
    if (wave == 0) {
        float v = s[0][lane] + s[1][lane] + s[2][lane] + s[3][lane];
        float c = (float)(end - beg);
        out[g * 64 + lane] = v / fmaxf(c, 1.0f);
    }
}

// ---------------- launch ----------------
extern "C" void kernel_launch(void* const* d_in, const int* in_sizes, int n_in,
                              void* d_out, int out_size, void* d_ws, size_t ws_size,
                              hipStream_t stream) {
    const float* x = (const float*)d_in[0];
    const int* ei = (const int*)d_in[1];
    const int* batch = (const int*)d_in[2];
    const float* W1 = (const float*)d_in[3];
    const float* b1 = (const float*)d_in[4];
    const float* W2 = (const float*)d_in[5];
    const float* b2 = (const float*)d_in[6];
    const float* W3 = (const float*)d_in[7];
    const float* b3 = (const float*)d_in[8];
    const float* W4 = (const float*)d_in[9];
    const float* b4 = (const float*)d_in[10];

    const int N = N_NODES, E = N_EDGES;
    const int* src = ei;
    const int* dst = ei + E;

    // workspace layout
    unsigned short* T = (unsigned short*)d_ws;    // N*128 bf16 (12.8 MB)
    float* H = (float*)(T + (size_t)N * 128);     // N*128 f32
    int* degi = (int*)(H + (size_t)N * 128);      // N i32
    float* dis = (float*)(degi + N);              // N f32
    int* rowptr = (int*)(dis + N);                // N+1 i32
    int* cursor = rowptr + (N + 1);               // N i32
    int* excl = cursor + N;                       // N i32
    int* bsum = excl + N;                         // 256 i32
    int* boff = bsum + 256;                       // 256 i32
    int2* csr = (int2*)(boff + 256);              // E int2
    int* gstart = (int*)(csr + E);                // 65 i32

    hipMemsetAsync(degi, 0, N * sizeof(int), stream);

    // ---- CSR build (once, reused by all 4 layers) ----
    const int NB = (N + 255) / 256;  // 196
    deg_count<<<(E + 255) / 256, 256, 0, stream>>>(dst, degi, E);
    dis_kernel<<<NB, 256, 0, stream>>>(degi, dis, N);
    scan_block<<<NB, 256, 0, stream>>>(degi, excl, bsum, N);
    scan_top<<<1, 256, 0, stream>>>(bsum, boff, NB);
    scan_fix<<<NB, 256, 0, stream>>>(excl, boff, rowptr, cursor, N, E);
    csr_fill<<<(E + 255) / 256, 256, 0, stream>>>(src, dst, dis, cursor, csr, E);
    graph_bounds<<<1, 128, 0, stream>>>(batch, gstart, N);

    const int MMG = (N + 63) / 64;         // mm: 64 nodes per block
    const int AGG = (N * 64 + 255) / 256;  // agg: 4 nodes per block

    // layer 1: input x (no relu)
    mm_kernel<32, false><<<MMG, 256, 0, stream>>>(x, W1, T, N);
    agg_kernel<128><<<AGG, 256, 0, stream>>>(rowptr, csr, dis, b1, T, H, N);

    // layer 2
    mm_kernel<32, true><<<MMG, 256, 0, stream>>>(H, W2, T, N);
    agg_kernel<128><<<AGG, 256, 0, stream>>>(rowptr, csr, dis, b2, T, H, N);

    // layer 3
    mm_kernel<32, true><<<MMG, 256, 0, stream>>>(H, W3, T, N);
    agg_kernel<128><<<AGG, 256, 0, stream>>>(rowptr, csr, dis, b3, T, H, N);

    // layer 4 (F=64, no relu after)
    mm_kernel<16, true><<<MMG, 256, 0, stream>>>(H, W4, T, N);
    agg_kernel<64><<<AGG, 256, 0, stream>>>(rowptr, csr, dis, b4, T, H, N);

    // global mean pool (no atomics; batch sorted)
    pool_graph<<<N_GRAPHS, 256, 0, stream>>>(H, gstart, (float*)d_out);
}

// Round 5
// 271.709 us; speedup vs baseline: 7.3466x; 1.3599x over previous
//
#include <hip/hip_runtime.h>
#include <hip/hip_bf16.h>

// ---------------- constants ----------------
#define N_NODES 50000
#define N_EDGES 600000
#define N_GRAPHS 64
#define PCHUNK 16

typedef __attribute__((ext_vector_type(8))) short bf16x8;
typedef __attribute__((ext_vector_type(4))) float f32x4;

// ---------------- bf16 helpers (round-to-nearest-even) ----------------
__device__ __forceinline__ unsigned short f2bf(float f) {
    unsigned int u = __float_as_uint(f);
    unsigned int r = u + 0x7fffu + ((u >> 16) & 1u);
    return (unsigned short)(r >> 16);
}
__device__ __forceinline__ float bf_lo(unsigned int u) { return __uint_as_float(u << 16); }
__device__ __forceinline__ float bf_hi(unsigned int u) { return __uint_as_float(u & 0xffff0000u); }
__device__ __forceinline__ float bf1(unsigned short s) {
    return __uint_as_float((unsigned int)s << 16);
}

// ---------------- degree / norm ----------------
__global__ __launch_bounds__(256) void deg_count(const int* __restrict__ dst,
                                                 int* __restrict__ degi, int E) {
    int i = blockIdx.x * blockDim.x + threadIdx.x;
    if (i < E) atomicAdd(&degi[dst[i]], 1);
}

__global__ __launch_bounds__(256) void dis_kernel(const int* __restrict__ degi,
                                                  float* __restrict__ dis, int N) {
    int i = blockIdx.x * blockDim.x + threadIdx.x;
    if (i < N) dis[i] = rsqrtf((float)degi[i] + 1.0f);
}

// ---------------- prefix scan (3-kernel hierarchical) ----------------
__global__ __launch_bounds__(256) void scan_block(const int* __restrict__ in,
                                                  int* __restrict__ excl,
                                                  int* __restrict__ bsum, int N) {
    __shared__ int s[256];
    int i = blockIdx.x * 256 + threadIdx.x;
    int v = (i < N) ? in[i] : 0;
    s[threadIdx.x] = v;
    __syncthreads();
#pragma unroll
    for (int off = 1; off < 256; off <<= 1) {
        int t = (threadIdx.x >= off) ? s[threadIdx.x - off] : 0;
        __syncthreads();
        s[threadIdx.x] += t;
        __syncthreads();
    }
    if (i < N) excl[i] = s[threadIdx.x] - v;
    if (threadIdx.x == 255) bsum[blockIdx.x] = s[255];
}

__global__ __launch_bounds__(256) void scan_top(const int* __restrict__ bsum,
                                                int* __restrict__ boff, int NB) {
    __shared__ int s[256];
    int v = (threadIdx.x < NB) ? bsum[threadIdx.x] : 0;
    s[threadIdx.x] = v;
    __syncthreads();
#pragma unroll
    for (int off = 1; off < 256; off <<= 1) {
        int t = (threadIdx.x >= off) ? s[threadIdx.x - off] : 0;
        __syncthreads();
        s[threadIdx.x] += t;
        __syncthreads();
    }
    if (threadIdx.x < NB) boff[threadIdx.x] = s[threadIdx.x] - v;
}

__global__ __launch_bounds__(256) void scan_fix(const int* __restrict__ excl,
                                                const int* __restrict__ boff,
                                                int* __restrict__ rowptr,
                                                int* __restrict__ cursor, int N, int E) {
    int i = blockIdx.x * 256 + threadIdx.x;
    if (i < N) {
        int r = excl[i] + boff[blockIdx.x];
        rowptr[i] = r;
        cursor[i] = r;
    }
    if (i == 0) rowptr[N] = E;
}

// ---------------- CSR fill: pack {src, norm} per edge ----------------
__global__ __launch_bounds__(256) void csr_fill(const int* __restrict__ src,
                                                const int* __restrict__ dst,
                                                const float* __restrict__ dis,
                                                int* __restrict__ cursor,
                                                int2* __restrict__ csr, int E) {
    int e = blockIdx.x * blockDim.x + threadIdx.x;
    if (e >= E) return;
    int s = src[e];
    int d = dst[e];
    float nrm = dis[s] * dis[d];
    int pos = atomicAdd(&cursor[d], 1);
    csr[pos] = make_int2(s, __float_as_int(nrm));
}

// ---------------- weight repack: f32 W[128][F] -> bf16 B-fragment layout ----------------
// Wp[((ct*4+ks)*64 + lane)*8 + i] = bf16( W[ks*32 + (lane>>4)*8 + i][ct*16 + (lane&15)] )
template <int F>
__global__ __launch_bounds__(256) void wprep(const float* __restrict__ W,
                                             unsigned short* __restrict__ Wp) {
    int idx = blockIdx.x * 256 + threadIdx.x;
    if (idx >= F * 128) return;
    int i = idx & 7;
    int lane = (idx >> 3) & 63;
    int ks = (idx >> 9) & 3;
    int ct = idx >> 11;
    int k = ks * 32 + (lane >> 4) * 8 + i;
    int col = ct * 16 + (lane & 15);
    Wp[idx] = f2bf(W[(size_t)k * F + col]);
}

// ---------------- MFMA matmul: T(bf16) = relu?(X_f32) @ W ----------------
// block = 4 waves; wave w owns rows [blockIdx*64 + w*16, +16), all F cols.
// mfma_f32_16x16x32_bf16 layouts (m89/m91-verified):
//   A: row=lane&15, k = 8*(lane>>4)+i ; B: col=lane&15, same k ;
//   D: col=lane&15, row = 4*(lane>>4)+reg
template <int F, bool RELU>
__global__ __launch_bounds__(256) void mm_mfma(const float* __restrict__ X,
                                               const unsigned short* __restrict__ Wp,
                                               unsigned short* __restrict__ T, int N) {
    const int lane = threadIdx.x & 63;
    const int wave = threadIdx.x >> 6;
    const int r0 = blockIdx.x * 64 + wave * 16;
    const int kg = lane >> 4;
    const int rdrow = min(r0 + (lane & 15), N - 1);
    const float* xr = X + (size_t)rdrow * 128;

    bf16x8 a[4];
#pragma unroll
    for (int ks = 0; ks < 4; ++ks) {
        const int kb = ks * 32 + kg * 8;
        float4 x0 = *reinterpret_cast<const float4*>(xr + kb);
        float4 x1 = *reinterpret_cast<const float4*>(xr + kb + 4);
        float v[8] = {x0.x, x0.y, x0.z, x0.w, x1.x, x1.y, x1.z, x1.w};
#pragma unroll
        for (int i = 0; i < 8; ++i) {
            float f = RELU ? fmaxf(v[i], 0.0f) : v[i];
            a[ks][i] = (short)f2bf(f);
        }
    }

#pragma unroll
    for (int ct = 0; ct < F / 16; ++ct) {
        f32x4 acc = {0.f, 0.f, 0.f, 0.f};
#pragma unroll
        for (int ks = 0; ks < 4; ++ks) {
            bf16x8 b = *reinterpret_cast<const bf16x8*>(Wp + ((size_t)(ct * 4 + ks) * 64 + lane) * 8);
            acc = __builtin_amdgcn_mfma_f32_16x16x32_bf16(a[ks], b, acc, 0, 0, 0);
        }
        const int col = ct * 16 + (lane & 15);
#pragma unroll
        for (int r = 0; r < 4; ++r) {
            const int rowm = r0 + kg * 4 + r;
            if (rowm < N) T[(size_t)rowm * F + col] = f2bf(acc[r]);
        }
    }
}

// ---------------- gather aggregation (bf16 rows, f32 accumulate) ----------------
template <int F>
__global__ __launch_bounds__(256) void agg_kernel(const int* __restrict__ rowptr,
                                                  const int2* __restrict__ csr,
                                                  const float* __restrict__ dis,
                                                  const float* __restrict__ b,
                                                  const unsigned short* __restrict__ T,
                                                  float* __restrict__ H, int N) {
    const int lane = threadIdx.x & 63;
    const int node = (blockIdx.x * 256 + threadIdx.x) >> 6;
    if (node >= N) return;

    const int beg = rowptr[node];
    const int end = rowptr[node + 1];
    const float d = dis[node];
    const float d2 = d * d;

    if (F == 128) {
        unsigned int selfv =
            *reinterpret_cast<const unsigned int*>(T + (size_t)node * 128 + lane * 2);
        float2 bb = *reinterpret_cast<const float2*>(b + lane * 2);
        float ax = fmaf(bf_lo(selfv), d2, bb.x);
        float ay = fmaf(bf_hi(selfv), d2, bb.y);

        int p = beg;
        for (; p + 4 <= end; p += 4) {
            int2 e0 = csr[p], e1 = csr[p + 1], e2 = csr[p + 2], e3 = csr[p + 3];
            unsigned int r0 =
                *reinterpret_cast<const unsigned int*>(T + (size_t)e0.x * 128 + lane * 2);
            unsigned int r1 =
                *reinterpret_cast<const unsigned int*>(T + (size_t)e1.x * 128 + lane * 2);
            unsigned int r2 =
                *reinterpret_cast<const unsigned int*>(T + (size_t)e2.x * 128 + lane * 2);
            unsigned int r3 =
                *reinterpret_cast<const unsigned int*>(T + (size_t)e3.x * 128 + lane * 2);
            float n0 = __int_as_float(e0.y), n1 = __int_as_float(e1.y);
            float n2 = __int_as_float(e2.y), n3 = __int_as_float(e3.y);
            ax = fmaf(n0, bf_lo(r0), ax); ay = fmaf(n0, bf_hi(r0), ay);
            ax = fmaf(n1, bf_lo(r1), ax); ay = fmaf(n1, bf_hi(r1), ay);
            ax = fmaf(n2, bf_lo(r2), ax); ay = fmaf(n2, bf_hi(r2), ay);
            ax = fmaf(n3, bf_lo(r3), ax); ay = fmaf(n3, bf_hi(r3), ay);
        }
        for (; p < end; ++p) {
            int2 ed = csr[p];
            float nrm = __int_as_float(ed.y);
            unsigned int r =
                *reinterpret_cast<const unsigned int*>(T + (size_t)ed.x * 128 + lane * 2);
            ax = fmaf(nrm, bf_lo(r), ax);
            ay = fmaf(nrm, bf_hi(r), ay);
        }
        *reinterpret_cast<float2*>(H + (size_t)node * 128 + lane * 2) = make_float2(ax, ay);
    } else {  // F == 64
        float a = fmaf(bf1(T[(size_t)node * 64 + lane]), d2, b[lane]);

        int p = beg;
        for (; p + 4 <= end; p += 4) {
            int2 e0 = csr[p], e1 = csr[p + 1], e2 = csr[p + 2], e3 = csr[p + 3];
            unsigned short v0 = T[(size_t)e0.x * 64 + lane];
            unsigned short v1 = T[(size_t)e1.x * 64 + lane];
            unsigned short v2 = T[(size_t)e2.x * 64 + lane];
            unsigned short v3 = T[(size_t)e3.x * 64 + lane];
            a = fmaf(__int_as_float(e0.y), bf1(v0), a);
            a = fmaf(__int_as_float(e1.y), bf1(v1), a);
            a = fmaf(__int_as_float(e2.y), bf1(v2), a);
            a = fmaf(__int_as_float(e3.y), bf1(v3), a);
        }
        for (; p < end; ++p) {
            int2 ed = csr[p];
            a = fmaf(__int_as_float(ed.y), bf1(T[(size_t)ed.x * 64 + lane]), a);
        }
        H[(size_t)node * 64 + lane] = a;
    }
}

// ---------------- pooling (batch sorted; two-stage deterministic) ----------------
__global__ __launch_bounds__(128) void graph_bounds(const int* __restrict__ batch,
                                                    int* __restrict__ gstart, int N) {
    int g = threadIdx.x;
    if (g > N_GRAPHS) return;
    int lo = 0, hi = N;
    while (lo < hi) {
        int mid = (lo + hi) >> 1;
        if (batch[mid] < g) lo = mid + 1; else hi = mid;
    }
    gstart[g] = lo;
}

// grid = N_GRAPHS * PCHUNK blocks; block = 4 waves; lane = feature
__global__ __launch_bounds__(256) void pool_partial(const float* __restrict__ H,
                                                    const int* __restrict__ gstart,
                                                    float* __restrict__ partial) {
    const int g = blockIdx.x >> 4;
    const int c = blockIdx.x & (PCHUNK - 1);
    const int beg = gstart[g], end = gstart[g + 1];
    const int len = end - beg;
    const int csz = (len + PCHUNK - 1) / PCHUNK;
    const int cb = beg + c * csz;
    const int ce = min(cb + csz, end);
    const int lane = threadIdx.x & 63;
    const int wave = threadIdx.x >> 6;

    float acc = 0.0f;
    for (int n = cb + wave; n < ce; n += 4)
        acc += H[(size_t)n * 64 + lane];

    __shared__ float s[4][64];
    s[wave][lane] = acc;
    __syncthreads();
    if (wave == 0)
        partial[(size_t)(g * PCHUNK + c) * 64 + lane] =
            s[0][lane] + s[1][lane] + s[2][lane] + s[3][lane];
}

__global__ __launch_bounds__(64) void pool_fin(const float* __restrict__ partial,
                                               const int* __restrict__ gstart,
                                               float* __restrict__ out) {
    const int g = blockIdx.x;
    const int lane = threadIdx.x;
    float v = 0.0f;
#pragma unroll
    for (int c = 0; c < PCHUNK; ++c) v += partial[(size_t)(g * PCHUNK + c) * 64 + lane];
    float cnt = (float)(gstart[g + 1] - gstart[g]);
    out[g * 64 + lane] = v / fmaxf(cnt, 1.0f);
}

// ---------------- launch ----------------
extern "C" void kernel_launch(void* const* d_in, const int* in_sizes, int n_in,
                              void* d_out, int out_size, void* d_ws, size_t ws_size,
                              hipStream_t stream) {
    const float* x = (const float*)d_in[0];
    const int* ei = (const int*)d_in[1];
    const int* batch = (const int*)d_in[2];
    const float* W1 = (const float*)d_in[3];
    const float* b1 = (const float*)d_in[4];
    const float* W2 = (const float*)d_in[5];
    const float* b2 = (const float*)d_in[6];
    const float* W3 = (const float*)d_in[7];
    const float* b3 = (const float*)d_in[8];
    const float* W4 = (const float*)d_in[9];
    const float* b4 = (const float*)d_in[10];

    const int N = N_NODES, E = N_EDGES;
    const int* src = ei;
    const int* dst = ei + E;

    // workspace layout (64B-aligned carve-outs)
    char* base = (char*)d_ws;
    size_t off = 0;
    auto carve = [&](size_t bytes) -> void* {
        off = (off + 63) & ~(size_t)63;
        void* p = base + off;
        off += bytes;
        return p;
    };
    unsigned short* T = (unsigned short*)carve((size_t)N * 128 * 2);
    float* H = (float*)carve((size_t)N * 128 * 4);
    int* degi = (int*)carve((size_t)N * 4);
    float* dis = (float*)carve((size_t)N * 4);
    int* rowptr = (int*)carve((size_t)(N + 1) * 4);
    int* cursor = (int*)carve((size_t)N * 4);
    int* excl = (int*)carve((size_t)N * 4);
    int* bsum = (int*)carve(256 * 4);
    int* boff = (int*)carve(256 * 4);
    int2* csr = (int2*)carve((size_t)E * 8);
    int* gstart = (int*)carve(65 * 4);
    float* partial = (float*)carve((size_t)N_GRAPHS * PCHUNK * 64 * 4);
    unsigned short* Wp1 = (unsigned short*)carve(128 * 128 * 2);
    unsigned short* Wp2 = (unsigned short*)carve(128 * 128 * 2);
    unsigned short* Wp3 = (unsigned short*)carve(128 * 128 * 2);
    unsigned short* Wp4 = (unsigned short*)carve(128 * 64 * 2);

    hipMemsetAsync(degi, 0, N * sizeof(int), stream);

    // ---- one-time prep: CSR build + weight repack ----
    const int NB = (N + 255) / 256;  // 196
    deg_count<<<(E + 255) / 256, 256, 0, stream>>>(dst, degi, E);
    dis_kernel<<<NB, 256, 0, stream>>>(degi, dis, N);
    scan_block<<<NB, 256, 0, stream>>>(degi, excl, bsum, N);
    scan_top<<<1, 256, 0, stream>>>(bsum, boff, NB);
    scan_fix<<<NB, 256, 0, stream>>>(excl, boff, rowptr, cursor, N, E);
    csr_fill<<<(E + 255) / 256, 256, 0, stream>>>(src, dst, dis, cursor, csr, E);
    graph_bounds<<<1, 128, 0, stream>>>(batch, gstart, N);
    wprep<128><<<64, 256, 0, stream>>>(W1, Wp1);
    wprep<128><<<64, 256, 0, stream>>>(W2, Wp2);
    wprep<128><<<64, 256, 0, stream>>>(W3, Wp3);
    wprep<64><<<32, 256, 0, stream>>>(W4, Wp4);

    const int MMG = (N + 63) / 64;         // mm: 64 nodes per block
    const int AGG = (N * 64 + 255) / 256;  // agg: 4 nodes per block

    // layer 1: input x (no relu)
    mm_mfma<128, false><<<MMG, 256, 0, stream>>>(x, Wp1, T, N);
    agg_kernel<128><<<AGG, 256, 0, stream>>>(rowptr, csr, dis, b1, T, H, N);

    // layer 2
    mm_mfma<128, true><<<MMG, 256, 0, stream>>>(H, Wp2, T, N);
    agg_kernel<128><<<AGG, 256, 0, stream>>>(rowptr, csr, dis, b2, T, H, N);

    // layer 3
    mm_mfma<128, true><<<MMG, 256, 0, stream>>>(H, Wp3, T, N);
    agg_kernel<128><<<AGG, 256, 0, stream>>>(rowptr, csr, dis, b3, T, H, N);

    // layer 4 (F=64, no relu after)
    mm_mfma<64, true><<<MMG, 256, 0, stream>>>(H, Wp4, T, N);
    agg_kernel<64><<<AGG, 256, 0, stream>>>(rowptr, csr, dis, b4, T, H, N);

    // global mean pool (two-stage, deterministic)
    pool_partial<<<N_GRAPHS * PCHUNK, 256, 0, stream>>>(H, gstart, partial);
    pool_fin<<<N_GRAPHS, 64, 0, stream>>>(partial, gstart, (float*)d_out);
}

// Round 6
// 238.109 us; speedup vs baseline: 8.3834x; 1.1411x over previous
//
#include <hip/hip_runtime.h>
#include <hip/hip_bf16.h>

// ---------------- constants ----------------
#define N_NODES 50000
#define N_EDGES 600000
#define N_GRAPHS 64
#define PCHUNK 16

typedef __attribute__((ext_vector_type(8))) short bf16x8;
typedef __attribute__((ext_vector_type(4))) float f32x4;

// ---------------- bf16 helpers (round-to-nearest-even) ----------------
__device__ __forceinline__ unsigned short f2bf(float f) {
    unsigned int u = __float_as_uint(f);
    unsigned int r = u + 0x7fffu + ((u >> 16) & 1u);
    return (unsigned short)(r >> 16);
}
__device__ __forceinline__ float bf_lo(unsigned int u) { return __uint_as_float(u << 16); }
__device__ __forceinline__ float bf_hi(unsigned int u) { return __uint_as_float(u & 0xffff0000u); }
__device__ __forceinline__ float bf1(unsigned short s) {
    return __uint_as_float((unsigned int)s << 16);
}

// ---------------- degree ----------------
__global__ __launch_bounds__(256) void deg_count(const int* __restrict__ dst,
                                                 int* __restrict__ degi, int E) {
    int i = blockIdx.x * blockDim.x + threadIdx.x;
    if (i < E) atomicAdd(&degi[dst[i]], 1);
}

// ---------------- prefix scan (fused extras) ----------------
// scan_block also computes dis = rsqrt(deg+1)
__global__ __launch_bounds__(256) void scan_block(const int* __restrict__ in,
                                                  int* __restrict__ excl,
                                                  int* __restrict__ bsum,
                                                  float* __restrict__ dis, int N) {
    __shared__ int s[256];
    int i = blockIdx.x * 256 + threadIdx.x;
    int v = (i < N) ? in[i] : 0;
    s[threadIdx.x] = v;
    __syncthreads();
#pragma unroll
    for (int off = 1; off < 256; off <<= 1) {
        int t = (threadIdx.x >= off) ? s[threadIdx.x - off] : 0;
        __syncthreads();
        s[threadIdx.x] += t;
        __syncthreads();
    }
    if (i < N) {
        excl[i] = s[threadIdx.x] - v;
        dis[i] = rsqrtf((float)v + 1.0f);
    }
    if (threadIdx.x == 255) bsum[blockIdx.x] = s[255];
}

// scan_top also does the graph_bounds binary searches (batch sorted)
__global__ __launch_bounds__(256) void scan_top(const int* __restrict__ bsum,
                                                int* __restrict__ boff, int NB,
                                                const int* __restrict__ batch,
                                                int* __restrict__ gstart, int N) {
    __shared__ int s[256];
    int v = (threadIdx.x < NB) ? bsum[threadIdx.x] : 0;
    s[threadIdx.x] = v;
    __syncthreads();
#pragma unroll
    for (int off = 1; off < 256; off <<= 1) {
        int t = (threadIdx.x >= off) ? s[threadIdx.x - off] : 0;
        __syncthreads();
        s[threadIdx.x] += t;
        __syncthreads();
    }
    if (threadIdx.x < NB) boff[threadIdx.x] = s[threadIdx.x] - v;

    int g = threadIdx.x;
    if (g <= N_GRAPHS) {
        int lo = 0, hi = N;
        while (lo < hi) {
            int mid = (lo + hi) >> 1;
            if (batch[mid] < g) lo = mid + 1; else hi = mid;
        }
        gstart[g] = lo;
    }
}

__global__ __launch_bounds__(256) void scan_fix(const int* __restrict__ excl,
                                                const int* __restrict__ boff,
                                                int* __restrict__ rowptr,
                                                int* __restrict__ cursor, int N, int E) {
    int i = blockIdx.x * 256 + threadIdx.x;
    if (i < N) {
        int r = excl[i] + boff[blockIdx.x];
        rowptr[i] = r;
        cursor[i] = r;
    }
    if (i == 0) rowptr[N] = E;
}

// ---------------- CSR fill: pack {src, norm} per edge ----------------
__global__ __launch_bounds__(256) void csr_fill(const int* __restrict__ src,
                                                const int* __restrict__ dst,
                                                const float* __restrict__ dis,
                                                int* __restrict__ cursor,
                                                int2* __restrict__ csr, int E) {
    int e = blockIdx.x * blockDim.x + threadIdx.x;
    if (e >= E) return;
    int s = src[e];
    int d = dst[e];
    float nrm = dis[s] * dis[d];
    int pos = atomicAdd(&cursor[d], 1);
    csr[pos] = make_int2(s, __float_as_int(nrm));
}

// ---------------- weight repack (all 4 weights, one kernel) ----------------
// Wp[((ct*4+ks)*64 + lane)*8 + i] = bf16( W[ks*32 + (lane>>4)*8 + i][ct*16 + (lane&15)] )
__device__ __forceinline__ void wprep_one(const float* W, unsigned short* Wp, int F, int idx) {
    int i = idx & 7;
    int lane = (idx >> 3) & 63;
    int ks = (idx >> 9) & 3;
    int ct = idx >> 11;
    int k = ks * 32 + (lane >> 4) * 8 + i;
    int col = ct * 16 + (lane & 15);
    Wp[idx] = f2bf(W[(size_t)k * F + col]);
}

__global__ __launch_bounds__(256) void wprep_all(const float* __restrict__ W1,
                                                 const float* __restrict__ W2,
                                                 const float* __restrict__ W3,
                                                 const float* __restrict__ W4,
                                                 unsigned short* __restrict__ Wp1,
                                                 unsigned short* __restrict__ Wp2,
                                                 unsigned short* __restrict__ Wp3,
                                                 unsigned short* __restrict__ Wp4) {
    int bid = blockIdx.x;
    if (bid < 64) wprep_one(W1, Wp1, 128, bid * 256 + threadIdx.x);
    else if (bid < 128) wprep_one(W2, Wp2, 128, (bid - 64) * 256 + threadIdx.x);
    else if (bid < 192) wprep_one(W3, Wp3, 128, (bid - 128) * 256 + threadIdx.x);
    else wprep_one(W4, Wp4, 64, (bid - 192) * 256 + threadIdx.x);
}

// ---------------- MFMA matmul: T(bf16) = relu?(X) @ W ----------------
// block = 4 waves; wave w owns rows [blockIdx*64 + w*16, +16), all F cols.
// A: row=lane&15, k=8*(lane>>4)+i ; B: col=lane&15 same k ; D: col=lane&15, row=4*(lane>>4)+reg
template <int F, bool BF16IN, bool RELU>
__global__ __launch_bounds__(256) void mm_mfma(const float* __restrict__ Xf,
                                               const unsigned short* __restrict__ Xb,
                                               const unsigned short* __restrict__ Wp,
                                               unsigned short* __restrict__ T, int N) {
    const int lane = threadIdx.x & 63;
    const int wave = threadIdx.x >> 6;
    const int r0 = blockIdx.x * 64 + wave * 16;
    const int kg = lane >> 4;
    const int rdrow = min(r0 + (lane & 15), N - 1);

    bf16x8 a[4];
    if (BF16IN) {
        const unsigned short* hr = Xb + (size_t)rdrow * 128;
#pragma unroll
        for (int ks = 0; ks < 4; ++ks) {
            bf16x8 av = *reinterpret_cast<const bf16x8*>(hr + ks * 32 + kg * 8);
            if (RELU) {
#pragma unroll
                for (int i = 0; i < 8; ++i) av[i] = (av[i] < 0) ? (short)0 : av[i];
            }
            a[ks] = av;
        }
    } else {
        const float* xr = Xf + (size_t)rdrow * 128;
#pragma unroll
        for (int ks = 0; ks < 4; ++ks) {
            const int kb = ks * 32 + kg * 8;
            float4 x0 = *reinterpret_cast<const float4*>(xr + kb);
            float4 x1 = *reinterpret_cast<const float4*>(xr + kb + 4);
            float v[8] = {x0.x, x0.y, x0.z, x0.w, x1.x, x1.y, x1.z, x1.w};
#pragma unroll
            for (int i = 0; i < 8; ++i) {
                float f = RELU ? fmaxf(v[i], 0.0f) : v[i];
                a[ks][i] = (short)f2bf(f);
            }
        }
    }

#pragma unroll
    for (int ct = 0; ct < F / 16; ++ct) {
        f32x4 acc = {0.f, 0.f, 0.f, 0.f};
#pragma unroll
        for (int ks = 0; ks < 4; ++ks) {
            bf16x8 b = *reinterpret_cast<const bf16x8*>(Wp + ((size_t)(ct * 4 + ks) * 64 + lane) * 8);
            acc = __builtin_amdgcn_mfma_f32_16x16x32_bf16(a[ks], b, acc, 0, 0, 0);
        }
        const int col = ct * 16 + (lane & 15);
#pragma unroll
        for (int r = 0; r < 4; ++r) {
            const int rowm = r0 + kg * 4 + r;
            if (rowm < N) T[(size_t)rowm * F + col] = f2bf(acc[r]);
        }
    }
}

// ---------------- gather aggregation (bf16 rows -> f32 acc -> bf16 H) ----------------
// wave-uniform node pinned to SGPR so rowptr/csr go through the scalar cache.
template <int F>
__global__ __launch_bounds__(256) void agg_kernel(const int* __restrict__ rowptr,
                                                  const int2* __restrict__ csr,
                                                  const float* __restrict__ dis,
                                                  const float* __restrict__ b,
                                                  const unsigned short* __restrict__ T,
                                                  unsigned short* __restrict__ H, int N) {
    const int lane = threadIdx.x & 63;
    const int node = __builtin_amdgcn_readfirstlane((blockIdx.x * 256 + threadIdx.x) >> 6);
    if (node >= N) return;

    const int beg = rowptr[node];
    const int end = rowptr[node + 1];
    const float d = dis[node];
    const float d2 = d * d;

    if (F == 128) {
        unsigned int selfv =
            *reinterpret_cast<const unsigned int*>(T + (size_t)node * 128 + lane * 2);
        float2 bb = *reinterpret_cast<const float2*>(b + lane * 2);
        float ax = fmaf(bf_lo(selfv), d2, bb.x);
        float ay = fmaf(bf_hi(selfv), d2, bb.y);

        int p = beg;
        for (; p + 8 <= end; p += 8) {
            int2 e0 = csr[p], e1 = csr[p + 1], e2 = csr[p + 2], e3 = csr[p + 3];
            int2 e4 = csr[p + 4], e5 = csr[p + 5], e6 = csr[p + 6], e7 = csr[p + 7];
            unsigned int r0 = *reinterpret_cast<const unsigned int*>(T + (size_t)e0.x * 128 + lane * 2);
            unsigned int r1 = *reinterpret_cast<const unsigned int*>(T + (size_t)e1.x * 128 + lane * 2);
            unsigned int r2 = *reinterpret_cast<const unsigned int*>(T + (size_t)e2.x * 128 + lane * 2);
            unsigned int r3 = *reinterpret_cast<const unsigned int*>(T + (size_t)e3.x * 128 + lane * 2);
            unsigned int r4 = *reinterpret_cast<const unsigned int*>(T + (size_t)e4.x * 128 + lane * 2);
            unsigned int r5 = *reinterpret_cast<const unsigned int*>(T + (size_t)e5.x * 128 + lane * 2);
            unsigned int r6 = *reinterpret_cast<const unsigned int*>(T + (size_t)e6.x * 128 + lane * 2);
            unsigned int r7 = *reinterpret_cast<const unsigned int*>(T + (size_t)e7.x * 128 + lane * 2);
            float n0 = __int_as_float(e0.y), n1 = __int_as_float(e1.y);
            float n2 = __int_as_float(e2.y), n3 = __int_as_float(e3.y);
            float n4 = __int_as_float(e4.y), n5 = __int_as_float(e5.y);
            float n6 = __int_as_float(e6.y), n7 = __int_as_float(e7.y);
            ax = fmaf(n0, bf_lo(r0), ax); ay = fmaf(n0, bf_hi(r0), ay);
            ax = fmaf(n1, bf_lo(r1), ax); ay = fmaf(n1, bf_hi(r1), ay);
            ax = fmaf(n2, bf_lo(r2), ax); ay = fmaf(n2, bf_hi(r2), ay);
            ax = fmaf(n3, bf_lo(r3), ax); ay = fmaf(n3, bf_hi(r3), ay);
            ax = fmaf(n4, bf_lo(r4), ax); ay = fmaf(n4, bf_hi(r4), ay);
            ax = fmaf(n5, bf_lo(r5), ax); ay = fmaf(n5, bf_hi(r5), ay);
            ax = fmaf(n6, bf_lo(r6), ax); ay = fmaf(n6, bf_hi(r6), ay);
            ax = fmaf(n7, bf_lo(r7), ax); ay = fmaf(n7, bf_hi(r7), ay);
        }
        for (; p + 4 <= end; p += 4) {
            int2 e0 = csr[p], e1 = csr[p + 1], e2 = csr[p + 2], e3 = csr[p + 3];
            unsigned int r0 = *reinterpret_cast<const unsigned int*>(T + (size_t)e0.x * 128 + lane * 2);
            unsigned int r1 = *reinterpret_cast<const unsigned int*>(T + (size_t)e1.x * 128 + lane * 2);
            unsigned int r2 = *reinterpret_cast<const unsigned int*>(T + (size_t)e2.x * 128 + lane * 2);
            unsigned int r3 = *reinterpret_cast<const unsigned int*>(T + (size_t)e3.x * 128 + lane * 2);
            float n0 = __int_as_float(e0.y), n1 = __int_as_float(e1.y);
            float n2 = __int_as_float(e2.y), n3 = __int_as_float(e3.y);
            ax = fmaf(n0, bf_lo(r0), ax); ay = fmaf(n0, bf_hi(r0), ay);
            ax = fmaf(n1, bf_lo(r1), ax); ay = fmaf(n1, bf_hi(r1), ay);
            ax = fmaf(n2, bf_lo(r2), ax); ay = fmaf(n2, bf_hi(r2), ay);
            ax = fmaf(n3, bf_lo(r3), ax); ay = fmaf(n3, bf_hi(r3), ay);
        }
        for (; p < end; ++p) {
            int2 ed = csr[p];
            float nrm = __int_as_float(ed.y);
            unsigned int r = *reinterpret_cast<const unsigned int*>(T + (size_t)ed.x * 128 + lane * 2);
            ax = fmaf(nrm, bf_lo(r), ax);
            ay = fmaf(nrm, bf_hi(r), ay);
        }
        unsigned int packed = ((unsigned int)f2bf(ay) << 16) | (unsigned int)f2bf(ax);
        *reinterpret_cast<unsigned int*>(H + (size_t)node * 128 + lane * 2) = packed;
    } else {  // F == 64
        float a = fmaf(bf1(T[(size_t)node * 64 + lane]), d2, b[lane]);

        int p = beg;
        for (; p + 8 <= end; p += 8) {
            int2 e0 = csr[p], e1 = csr[p + 1], e2 = csr[p + 2], e3 = csr[p + 3];
            int2 e4 = csr[p + 4], e5 = csr[p + 5], e6 = csr[p + 6], e7 = csr[p + 7];
            unsigned short v0 = T[(size_t)e0.x * 64 + lane];
            unsigned short v1 = T[(size_t)e1.x * 64 + lane];
            unsigned short v2 = T[(size_t)e2.x * 64 + lane];
            unsigned short v3 = T[(size_t)e3.x * 64 + lane];
            unsigned short v4 = T[(size_t)e4.x * 64 + lane];
            unsigned short v5 = T[(size_t)e5.x * 64 + lane];
            unsigned short v6 = T[(size_t)e6.x * 64 + lane];
            unsigned short v7 = T[(size_t)e7.x * 64 + lane];
            a = fmaf(__int_as_float(e0.y), bf1(v0), a);
            a = fmaf(__int_as_float(e1.y), bf1(v1), a);
            a = fmaf(__int_as_float(e2.y), bf1(v2), a);
            a = fmaf(__int_as_float(e3.y), bf1(v3), a);
            a = fmaf(__int_as_float(e4.y), bf1(v4), a);
            a = fmaf(__int_as_float(e5.y), bf1(v5), a);
            a = fmaf(__int_as_float(e6.y), bf1(v6), a);
            a = fmaf(__int_as_float(e7.y), bf1(v7), a);
        }
        for (; p + 4 <= end; p += 4) {
            int2 e0 = csr[p], e1 = csr[p + 1], e2 = csr[p + 2], e3 = csr[p + 3];
            unsigned short v0 = T[(size_t)e0.x * 64 + lane];
            unsigned short v1 = T[(size_t)e1.x * 64 + lane];
            unsigned short v2 = T[(size_t)e2.x * 64 + lane];
            unsigned short v3 = T[(size_t)e3.x * 64 + lane];
            a = fmaf(__int_as_float(e0.y), bf1(v0), a);
            a = fmaf(__int_as_float(e1.y), bf1(v1), a);
            a = fmaf(__int_as_float(e2.y), bf1(v2), a);
            a = fmaf(__int_as_float(e3.y), bf1(v3), a);
        }
        for (; p < end; ++p) {
            int2 ed = csr[p];
            a = fmaf(__int_as_float(ed.y), bf1(T[(size_t)ed.x * 64 + lane]), a);
        }
        H[(size_t)node * 64 + lane] = f2bf(a);
    }
}

// ---------------- pooling (two-stage deterministic; H is bf16) ----------------
__global__ __launch_bounds__(256) void pool_partial(const unsigned short* __restrict__ H,
                                                    const int* __restrict__ gstart,
                                                    float* __restrict__ partial) {
    const int g = blockIdx.x >> 4;
    const int c = blockIdx.x & (PCHUNK - 1);
    const int beg = gstart[g], end = gstart[g + 1];
    const int len = end - beg;
    const int csz = (len + PCHUNK - 1) / PCHUNK;
    const int cb = beg + c * csz;
    const int ce = min(cb + csz, end);
    const int lane = threadIdx.x & 63;
    const int wave = threadIdx.x >> 6;

    float acc = 0.0f;
    for (int n = cb + wave; n < ce; n += 4)
        acc += bf1(H[(size_t)n * 64 + lane]);

    __shared__ float s[4][64];
    s[wave][lane] = acc;
    __syncthreads();
    if (wave == 0)
        partial[(size_t)(g * PCHUNK + c) * 64 + lane] =
            s[0][lane] + s[1][lane] + s[2][lane] + s[3][lane];
}

__global__ __launch_bounds__(64) void pool_fin(const float* __restrict__ partial,
                                               const int* __restrict__ gstart,
                                               float* __restrict__ out) {
    const int g = blockIdx.x;
    const int lane = threadIdx.x;
    float v = 0.0f;
#pragma unroll
    for (int c = 0; c < PCHUNK; ++c) v += partial[(size_t)(g * PCHUNK + c) * 64 + lane];
    float cnt = (float)(gstart[g + 1] - gstart[g]);
    out[g * 64 + lane] = v / fmaxf(cnt, 1.0f);
}

// ---------------- launch ----------------
extern "C" void kernel_launch(void* const* d_in, const int* in_sizes, int n_in,
                              void* d_out, int out_size, void* d_ws, size_t ws_size,
                              hipStream_t stream) {
    const float* x = (const float*)d_in[0];
    const int* ei = (const int*)d_in[1];
    const int* batch = (const int*)d_in[2];
    const float* W1 = (const float*)d_in[3];
    const float* b1 = (const float*)d_in[4];
    const float* W2 = (const float*)d_in[5];
    const float* b2 = (const float*)d_in[6];
    const float* W3 = (const float*)d_in[7];
    const float* b3 = (const float*)d_in[8];
    const float* W4 = (const float*)d_in[9];
    const float* b4 = (const float*)d_in[10];

    const int N = N_NODES, E = N_EDGES;
    const int* src = ei;
    const int* dst = ei + E;

    // workspace layout (64B-aligned carve-outs)
    char* base = (char*)d_ws;
    size_t off = 0;
    auto carve = [&](size_t bytes) -> void* {
        off = (off + 63) & ~(size_t)63;
        void* p = base + off;
        off += bytes;
        return p;
    };
    unsigned short* T = (unsigned short*)carve((size_t)N * 128 * 2);  // bf16
    unsigned short* H = (unsigned short*)carve((size_t)N * 128 * 2);  // bf16
    int* degi = (int*)carve((size_t)N * 4);
    float* dis = (float*)carve((size_t)N * 4);
    int* rowptr = (int*)carve((size_t)(N + 1) * 4);
    int* cursor = (int*)carve((size_t)N * 4);
    int* excl = (int*)carve((size_t)N * 4);
    int* bsum = (int*)carve(256 * 4);
    int* boff = (int*)carve(256 * 4);
    int2* csr = (int2*)carve((size_t)E * 8);
    int* gstart = (int*)carve(65 * 4);
    float* partial = (float*)carve((size_t)N_GRAPHS * PCHUNK * 64 * 4);
    unsigned short* Wp1 = (unsigned short*)carve(128 * 128 * 2);
    unsigned short* Wp2 = (unsigned short*)carve(128 * 128 * 2);
    unsigned short* Wp3 = (unsigned short*)carve(128 * 128 * 2);
    unsigned short* Wp4 = (unsigned short*)carve(128 * 64 * 2);

    hipMemsetAsync(degi, 0, N * sizeof(int), stream);

    // ---- one-time prep: CSR build + weight repack (consolidated) ----
    const int NB = (N + 255) / 256;  // 196
    deg_count<<<(E + 255) / 256, 256, 0, stream>>>(dst, degi, E);
    scan_block<<<NB, 256, 0, stream>>>(degi, excl, bsum, dis, N);
    scan_top<<<1, 256, 0, stream>>>(bsum, boff, NB, batch, gstart, N);
    scan_fix<<<NB, 256, 0, stream>>>(excl, boff, rowptr, cursor, N, E);
    csr_fill<<<(E + 255) / 256, 256, 0, stream>>>(src, dst, dis, cursor, csr, E);
    wprep_all<<<224, 256, 0, stream>>>(W1, W2, W3, W4, Wp1, Wp2, Wp3, Wp4);

    const int MMG = (N + 63) / 64;         // mm: 64 nodes per block
    const int AGG = (N * 64 + 255) / 256;  // agg: 4 nodes per block

    // layer 1: input x f32 (no relu)
    mm_mfma<128, false, false><<<MMG, 256, 0, stream>>>(x, nullptr, Wp1, T, N);
    agg_kernel<128><<<AGG, 256, 0, stream>>>(rowptr, csr, dis, b1, T, H, N);

    // layer 2
    mm_mfma<128, true, true><<<MMG, 256, 0, stream>>>(nullptr, H, Wp2, T, N);
    agg_kernel<128><<<AGG, 256, 0, stream>>>(rowptr, csr, dis, b2, T, H, N);

    // layer 3
    mm_mfma<128, true, true><<<MMG, 256, 0, stream>>>(nullptr, H, Wp3, T, N);
    agg_kernel<128><<<AGG, 256, 0, stream>>>(rowptr, csr, dis, b3, T, H, N);

    // layer 4 (F=64, no relu after)
    mm_mfma<64, true, true><<<MMG, 256, 0, stream>>>(nullptr, H, Wp4, T, N);
    agg_kernel<64><<<AGG, 256, 0, stream>>>(rowptr, csr, dis, b4, T, H, N);

    // global mean pool (two-stage, deterministic)
    pool_partial<<<N_GRAPHS * PCHUNK, 256, 0, stream>>>(H, gstart, partial);
    pool_fin<<<N_GRAPHS, 64, 0, stream>>>(partial, gstart, (float*)d_out);
}